// Round 1
// 803.949 us; speedup vs baseline: 1.1999x; 1.1999x over previous
//
#include <hip/hip_runtime.h>

// Problem constants
#define B_ 256
#define C_ 16
#define I_ 64
#define H_ 40
#define T_ 512
#define G_ 120   // 3*H

#define TT  16          // timesteps per chunk
#define NCH (T_ / TT)   // 32 chunks
#define NT  640         // threads per block (10 waves)

// LDS row strides (bf16 element units)
#define SX  72    // xa row stride: 144 B rows, 16B-aligned for ds_read_b128
#define SHB 72    // hbf row stride

typedef short bf16x8 __attribute__((ext_vector_type(8)));
typedef float f32x4  __attribute__((ext_vector_type(4)));

__device__ __forceinline__ unsigned short f2bf(float f) {
    unsigned u = __float_as_uint(f);
    unsigned r = (u + 0x7FFFu + ((u >> 16) & 1u)) >> 16;   // RNE
    return (unsigned short)r;
}
__device__ __forceinline__ float bf2f(unsigned s) {
    return __uint_as_float(s << 16);
}
__device__ __forceinline__ float sigf(float x) {
    return __builtin_amdgcn_rcpf(1.0f + __expf(-x));
}

// Gate-interleaved weight-row permutation: p = 4*k + gate (gate in {r,z,n,pad}),
// 160 rows = 10 MFMA tiles = 10 waves. D fragment (row=4*lq+reg, col=lm) then
// holds the full (r,z,n) triple for (b=lm, k=4*w+lq) in ONE lane -> the GRU
// cell update is lane-local (no gh LDS round trip, no R2 scatter phase), and
// the gi D-column is the lane's own batch -> gi lives in registers all chunk.
__global__ __launch_bounds__(NT, 1)
void gru_mfma_kernel(const float* __restrict__ x,
                     const float* __restrict__ Wih,
                     const float* __restrict__ Whh,
                     const float* __restrict__ bih,
                     const float* __restrict__ bhh,
                     const float* __restrict__ Wfc,
                     const float* __restrict__ bfc,
                     float* __restrict__ out)
{
    // LDS: 36.9 KB (xa) + 4.6 KB (hbf ping-pong) = 41.5 KB
    __shared__ __align__(16) unsigned short xa[256 * SX];
    __shared__ __align__(16) unsigned short hbf[2][16 * SHB];

    const int tid = threadIdx.x;
    const int c   = blockIdx.x >> 4;          // channel
    const int b0  = (blockIdx.x & 15) * 16;   // batch base
    const int w   = tid >> 6;                 // wave 0..9
    const int lan = tid & 63;
    const int lq  = lan >> 4;                 // quad 0..3
    const int lm  = lan & 15;
    const int k   = w * 4 + lq;               // this lane's hidden unit 0..39
                                              // (b = lm)

    // init h ping-pong buffers (incl. zero pad cols 40..71, never rewritten)
    for (int idx = tid; idx < 2 * 16 * SHB; idx += NT)
        ((unsigned short*)hbf)[idx] = 0;

    float hreg = 0.0f;   // fp32 master copy of h[b=lm][k]

    // ---- x prefetch machinery: 4096 float4 per chunk, 64B-contiguous per (b,i) ----
    float4 pf[7];
#define PREFETCH(T0)                                                           \
    {                                                                          \
        _Pragma("unroll")                                                      \
        for (int it = 0; it < 7; ++it) {                                       \
            int idx = tid + it * NT;                                           \
            if (idx < 4096) {                                                  \
                int q = idx & 3, i = (idx >> 2) & 63, b = idx >> 8;            \
                const float* p = x + ((((size_t)(b0 + b) * C_ + c) * I_ + i)   \
                                      * T_ + (T0) + q * 4);                    \
                pf[it] = *reinterpret_cast<const float4*>(p);                  \
            }                                                                  \
        }                                                                      \
    }

    PREFETCH(0);

    // ---- weight fragments (permuted rows p = 4k+gate); A row = lm, k = lq*8+j ----
    bf16x8 wihf[2], whhf[2];
    {
        const int p  = w * 16 + lm;
        const int pg = p & 3;        // gate (3 = pad row -> zeros)
        const int pk = p >> 2;       // hidden unit of this A-row
        #pragma unroll
        for (int ks = 0; ks < 2; ++ks) {
            bf16x8 a  = {0,0,0,0,0,0,0,0};
            bf16x8 hh = {0,0,0,0,0,0,0,0};
            if (pg < 3) {
                const float* wp = Wih + ((size_t)c * G_ + pg * H_ + pk) * I_ + ks * 32 + lq * 8;
                float4 v0 = *reinterpret_cast<const float4*>(wp);
                float4 v1 = *reinterpret_cast<const float4*>(wp + 4);
                a[0]=(short)f2bf(v0.x); a[1]=(short)f2bf(v0.y);
                a[2]=(short)f2bf(v0.z); a[3]=(short)f2bf(v0.w);
                a[4]=(short)f2bf(v1.x); a[5]=(short)f2bf(v1.y);
                a[6]=(short)f2bf(v1.z); a[7]=(short)f2bf(v1.w);
                if (ks == 0 || lq == 0) {   // Whh cols kk<40 only
                    const float* hp = Whh + ((size_t)c * G_ + pg * H_ + pk) * H_ + ks * 32 + lq * 8;
                    float4 u0 = *reinterpret_cast<const float4*>(hp);
                    float4 u1 = *reinterpret_cast<const float4*>(hp + 4);
                    hh[0]=(short)f2bf(u0.x); hh[1]=(short)f2bf(u0.y);
                    hh[2]=(short)f2bf(u0.z); hh[3]=(short)f2bf(u0.w);
                    hh[4]=(short)f2bf(u1.x); hh[5]=(short)f2bf(u1.y);
                    hh[6]=(short)f2bf(u1.z); hh[7]=(short)f2bf(u1.w);
                }
            }
            wihf[ks] = a;
            whhf[ks] = hh;
        }
    }

    // Recurrent-MFMA accumulator init: D row reg r of this lane = gate r of k.
    // r,z get bih+bhh (old-kernel parity); n gets bhh only; pad 0.
    f32x4 bias4;
    #pragma unroll
    for (int r = 0; r < 4; ++r) {
        float v = 0.0f;
        if (r < 3) v  = bhh[c * G_ + r * H_ + k];
        if (r < 2) v += bih[c * G_ + r * H_ + k];
        bias4[r] = v;
    }
    const float bihn = bih[c * G_ + 2 * H_ + k];
    const float wfck = Wfc[c * H_ + k];

    uint2 gi_reg[16];   // per-chunk input projections, bf16-packed {r,z | n,pad}

    for (int ch = 0; ch < NCH; ++ch) {
        // ---- stage x chunk into LDS, bf16, column-block XOR swizzle by q=t>>2 ----
        // (bank for u16 store = 4b + colp/2; XOR spreads the q-collisions)
        #pragma unroll
        for (int it = 0; it < 7; ++it) {
            int idx = tid + it * NT;
            if (idx < 4096) {
                int q = idx & 3, i = (idx >> 2) & 63, b = idx >> 8;
                int colp = (((i >> 3) ^ q) << 3) | (i & 7);
                float4 v = pf[it];
                unsigned short* xr = &xa[(q * 64 + b) * SX + colp]; // row t=4q+dt
                xr[0]       = f2bf(v.x);
                xr[16 * SX] = f2bf(v.y);
                xr[32 * SX] = f2bf(v.z);
                xr[48 * SX] = f2bf(v.w);
            }
        }
        __syncthreads();

        // issue next chunk's global loads; they fly under gi phase + 16 steps
        { int tn = (ch + 1 < NCH) ? (ch + 1) * TT : 0; PREFETCH(tn); }

        // ---- gi phase -> REGISTERS (D col lm == this lane's batch) ----
        #pragma unroll
        for (int nt = 0; nt < 16; ++nt) {
            const unsigned short* xp = &xa[(nt * 16 + lm) * SX + ((lq ^ (nt >> 2)) << 3)];
            bf16x8 xb0 = *reinterpret_cast<const bf16x8*>(xp);
            bf16x8 xb1 = *reinterpret_cast<const bf16x8*>(xp + 32);
            f32x4 acc = {0.f, 0.f, 0.f, 0.f};
            acc = __builtin_amdgcn_mfma_f32_16x16x32_bf16(wihf[0], xb0, acc, 0, 0, 0);
            acc = __builtin_amdgcn_mfma_f32_16x16x32_bf16(wihf[1], xb1, acc, 0, 0, 0);
            gi_reg[nt].x = (unsigned)f2bf(acc[0]) | ((unsigned)f2bf(acc[1]) << 16);
            gi_reg[nt].y = (unsigned)f2bf(acc[2]) | ((unsigned)f2bf(acc[3]) << 16);
        }
        // no barrier needed here: steps don't touch xa; hbf ordering comes from
        // the previous step barrier.

        // ---- 16 recurrent steps, ONE barrier each, ping-pong hbf ----
        #pragma unroll
        for (int tt = 0; tt < TT; ++tt) {
            const unsigned short* hp = &hbf[tt & 1][lm * SHB + lq * 8];
            bf16x8 h0 = *reinterpret_cast<const bf16x8*>(hp);
            bf16x8 h1 = {0,0,0,0,0,0,0,0};
            if (lq == 0)   // only kk=32..39 are live (A rows kk>=40 are zero)
                h1 = *reinterpret_cast<const bf16x8*>(&hbf[tt & 1][lm * SHB + 32]);
            f32x4 a1 = bias4;
            a1 = __builtin_amdgcn_mfma_f32_16x16x32_bf16(whhf[0], h0, a1, 0, 0, 0);
            f32x4 a2 = {0.f, 0.f, 0.f, 0.f};
            a2 = __builtin_amdgcn_mfma_f32_16x16x32_bf16(whhf[1], h1, a2, 0, 0, 0);
            uint2 gv = gi_reg[tt];
            float pre_r = a1[0] + a2[0] + bf2f(gv.x & 0xffffu);
            float pre_z = a1[1] + a2[1] + bf2f(gv.x >> 16);
            float h_n   = a1[2] + a2[2];
            float i_n   = bf2f(gv.y & 0xffffu) + bihn;
            float r = sigf(pre_r);
            float z = sigf(pre_z);
            float e = __expf(2.0f * (i_n + r * h_n));
            float n = 1.0f - 2.0f * __builtin_amdgcn_rcpf(e + 1.0f);   // tanh
            hreg = (1.0f - z) * n + z * hreg;
            hbf[(tt & 1) ^ 1][lm * SHB + k] = f2bf(hreg);
            __syncthreads();
        }
    }

    // ---- epilogue: y[b,c] = sigmoid(sum_k wfc[k]*h[b,k] + bfc[c]) ----
    float* red = reinterpret_cast<float*>(xa);   // reuse (needs 2560 B)
    red[tid] = hreg * wfck;                      // tid == k*16 + lm
    __syncthreads();
    if (tid < 16) {
        float s = bfc[c];
        #pragma unroll
        for (int kk = 0; kk < H_; ++kk) s += red[kk * 16 + tid];
        out[(b0 + tid) * C_ + c] = sigf(s);
    }
}

extern "C" void kernel_launch(void* const* d_in, const int* in_sizes, int n_in,
                              void* d_out, int out_size, void* d_ws, size_t ws_size,
                              hipStream_t stream) {
    const float* x   = (const float*)d_in[0];
    const float* Wih = (const float*)d_in[1];
    const float* Whh = (const float*)d_in[2];
    const float* bih = (const float*)d_in[3];
    const float* bhh = (const float*)d_in[4];
    const float* Wfc = (const float*)d_in[5];
    const float* bfc = (const float*)d_in[6];
    float* out = (float*)d_out;

    dim3 grid(C_ * (B_ / 16));   // 256 blocks = 1/CU
    dim3 block(NT);              // 640 threads = 10 waves
    gru_mfma_kernel<<<grid, block, 0, stream>>>(x, Wih, Whh, bih, bhh, Wfc, bfc, out);
}